// Round 17
// baseline (342.991 us; speedup 1.0000x reference)
//
#include <hip/hip_runtime.h>
#include <math.h>

#define BATCH 1024
#define VOCAB 100000
#define KDIM  300
#define TOPK  10

#define NKB    10            // K blocks of 32 (K padded 300 -> 320)
#define NCB_A  64            // 1024 rows / 16
#define NCC    392           // 256-col chunks
#define NCAND  (NCC*8)       // 3136 candidate u32s per row (8 per chunk)
#define NKF    24            // final quad rescore set -> 96 cols
#define NDOT   (NKF*4)       // 96 exact dots per row

typedef __attribute__((ext_vector_type(8))) short bf16x8;
typedef __attribute__((ext_vector_type(4))) float f32x4;
typedef unsigned long long u64;

#define GL2LDS(gsrc, ldst)                                                    \
    __builtin_amdgcn_global_load_lds(                                         \
        (const __attribute__((address_space(1))) void*)(gsrc),                \
        (__attribute__((address_space(3))) void*)(ldst), 16, 0, 0)

__device__ __forceinline__ ushort f2bf(float f) {
    union { float f; unsigned u; } v; v.f = f;
    unsigned r = v.u + 0x7FFFu + ((v.u >> 16) & 1u);  // RNE
    return (ushort)(r >> 16);
}

// depth-4 descending insert, SIGNED keys (sentinel 0)
__device__ __forceinline__ void ins4(int (&l)[4], int e) {
    if (e <= l[3]) return;
    bool g0 = e > l[0], g1 = e > l[1], g2 = e > l[2];
    l[3] = g2 ? l[2] : e;
    l[2] = g2 ? (g1 ? l[1] : e) : l[2];
    l[1] = g1 ? (g0 ? l[0] : e) : l[1];
    l[0] = g0 ? e : l[0];
}

// descending u64 insert, depth N, fully unrolled (sentinel 0)
template<int N>
__device__ __forceinline__ void pins64(u64 (&ks)[N], u64 k) {
    if (k <= ks[N-1]) return;
    #pragma unroll
    for (int p = N-1; p >= 0; --p) {
        bool gt  = k > ks[p];
        bool gtp = (p > 0) ? (k > ks[p-1]) : false;
        ks[p] = gt ? (gtp ? ks[p-1] : k) : ks[p];
    }
}

// ---------------------------------------------------------------------------
// Kernel 1 (round 17): A-ONLY fragment packer (16 blocks, ~0.7 MB).
// B conversion is fused into sim_gemm (its 185 MB round-trip was ~31 us of
// pure HBM for a re-layout the GEMM can do inline from L3-resident weight).
//   A frag (kb, rb16): ws_a[((kb*64 + rb16)*64 + lane)*8 .. +7]
// ---------------------------------------------------------------------------
__global__ __launch_bounds__(256)
void convert_a(const int* __restrict__ wordid, const float* __restrict__ weight,
               ushort* __restrict__ ws_a)
{
    const int t   = threadIdx.x;
    const int w   = t >> 6, l = t & 63;
    const int cb  = blockIdx.x * 4 + w;            // rowblock16 0..63

    const int r16  = l & 15;
    const int ksub = (l >> 4) * 8;

    const int row = wordid[cb*16 + r16];
    const float* src = weight + (size_t)row * KDIM;

    #pragma unroll
    for (int kb = 0; kb < NKB; ++kb) {
        const int k0 = kb*32 + ksub;
        float4 a = make_float4(0.f,0.f,0.f,0.f);
        float4 b = make_float4(0.f,0.f,0.f,0.f);
        if (k0 + 8 <= KDIM) {
            a = *reinterpret_cast<const float4*>(src + k0);
            b = *reinterpret_cast<const float4*>(src + k0 + 4);
        } else if (k0 + 4 <= KDIM) {
            a = *reinterpret_cast<const float4*>(src + k0);
        }
        uint4 o;
        o.x = (unsigned)f2bf(a.x) | ((unsigned)f2bf(a.y) << 16);
        o.y = (unsigned)f2bf(a.z) | ((unsigned)f2bf(a.w) << 16);
        o.z = (unsigned)f2bf(b.x) | ((unsigned)f2bf(b.y) << 16);
        o.w = (unsigned)f2bf(b.z) | ((unsigned)f2bf(b.w) << 16);
        *reinterpret_cast<uint4*>(&ws_a[((size_t)kb*64 + cb)*512 + (size_t)l*8]) = o;
    }
}

// ---------------------------------------------------------------------------
// Kernel 2 (round 17): B loaded fp32 DIRECT from weight and converted
// in-register (fuses convert_frags' B pass away). A staged via GL2LDS.
// Structure otherwise = r16 (de-barriered BK=64, double-buffered B regs,
// XCD-residency swizzle). B frag element: col = cb*16 + (lane&15),
// k = kbg*32 + (lane>>4)*8 + j  — lane-local, so fp32->bf16 is 2 float4
// loads + 8 f2bf per frag, no LDS round-trip.
// ---------------------------------------------------------------------------
__global__ __launch_bounds__(512, 2)
void sim_gemm(const ushort* __restrict__ ws_a, const float* __restrict__ weight,
              unsigned* __restrict__ cand)
{
    __shared__ __align__(16) char pool[65536];   // 2 x 32 KB A buffers

    const int id = blockIdx.x;
    const int cc = (id & 7) + ((id >> 5) << 3);   // col-chunk 0..391
    const int rc = (id >> 3) & 3;                 // row-chunk 0..3

    const int t    = threadIdx.x;
    const int wid  = t >> 6, lane = t & 63;
    const int wm   = wid >> 2, wn = wid & 3;
    const int l16  = lane & 15, lk = lane >> 4;

    // stage this wave's 4 of 32 A-slots of K-tile kt into LDS buffer buf
    auto stageA = [&](int kt, int buf) {
        #pragma unroll
        for (int j = 0; j < 4; ++j) {
            const int slot = wid*4 + j;
            char* ldst = pool + buf*32768 + slot*1024;
            const ushort* src = ws_a
                + ((size_t)(kt*2 + (slot>>4))*64 + rc*16 + (slot & 15))*512
                + (size_t)lane*8;
            GL2LDS(src, (ushort*)ldst);
        }
    };

    // load this wave's 8 B-frags of K-tile kt from fp32 weight, convert
    auto loadB = [&](int kt, bf16x8 (&b)[2][4]) {
        #pragma unroll
        for (int kb = 0; kb < 2; ++kb)
            #pragma unroll
            for (int nf = 0; nf < 4; ++nf) {
                const int col = (cc*16 + wn*4 + nf)*16 + l16;
                const int k0  = (kt*2 + kb)*32 + lk*8;
                float4 x = make_float4(0.f,0.f,0.f,0.f);
                float4 y = make_float4(0.f,0.f,0.f,0.f);
                if (col < VOCAB) {
                    const float* src = weight + (size_t)col*KDIM + k0;
                    if (k0 + 8 <= KDIM) {
                        x = *reinterpret_cast<const float4*>(src);
                        y = *reinterpret_cast<const float4*>(src + 4);
                    } else if (k0 + 4 <= KDIM) {
                        x = *reinterpret_cast<const float4*>(src);
                    }
                }
                uint4 o;
                o.x = (unsigned)f2bf(x.x) | ((unsigned)f2bf(x.y) << 16);
                o.y = (unsigned)f2bf(x.z) | ((unsigned)f2bf(x.w) << 16);
                o.z = (unsigned)f2bf(y.x) | ((unsigned)f2bf(y.y) << 16);
                o.w = (unsigned)f2bf(y.z) | ((unsigned)f2bf(y.w) << 16);
                b[kb][nf] = *reinterpret_cast<bf16x8*>(&o);
            }
    };

    f32x4 acc[8][4] = {};
    bf16x8 bA[2][4], bB[2][4];

    // prologue: A kt0 -> LDS buf0, B kt0 -> regs
    stageA(0, 0);
    loadB(0, bA);
    asm volatile("s_waitcnt vmcnt(0)" ::: "memory");
    __builtin_amdgcn_s_barrier();
    asm volatile("" ::: "memory");

    #pragma unroll
    for (int kt = 0; kt < 5; ++kt) {
        const int buf = kt & 1;
        const ushort* Ab = (const ushort*)(pool + buf*32768);
        bf16x8 (&bcur)[2][4] = (kt & 1) ? bB : bA;   // kt unrolled -> static
        bf16x8 (&bnxt)[2][4] = (kt & 1) ? bA : bB;

        if (kt < 4) {
            stageA(kt + 1, buf ^ 1);
            loadB(kt + 1, bnxt);
        }

        #pragma unroll
        for (int p = 0; p < 4; ++p) {
            bf16x8 af[2][2];
            #pragma unroll
            for (int kb = 0; kb < 2; ++kb)
                #pragma unroll
                for (int m2 = 0; m2 < 2; ++m2)
                    af[kb][m2] = *reinterpret_cast<const bf16x8*>(
                        Ab + (size_t)(kb*16 + wm*8 + p*2 + m2)*512 + lane*8);

            __builtin_amdgcn_s_setprio(1);
            #pragma unroll
            for (int m2 = 0; m2 < 2; ++m2)
                #pragma unroll
                for (int nf = 0; nf < 4; ++nf) {
                    acc[p*2+m2][nf] = __builtin_amdgcn_mfma_f32_16x16x32_bf16(
                        bcur[0][nf], af[0][m2], acc[p*2+m2][nf], 0, 0, 0);
                    acc[p*2+m2][nf] = __builtin_amdgcn_mfma_f32_16x16x32_bf16(
                        bcur[1][nf], af[1][m2], acc[p*2+m2][nf], 0, 0, 0);
                }
            __builtin_amdgcn_s_setprio(0);
        }

        // K-tile boundary: A stages + B loads drained, publish
        if (kt < 4) {
            asm volatile("s_waitcnt vmcnt(0)" ::: "memory");
            __builtin_amdgcn_s_barrier();
            asm volatile("" ::: "memory");
        }
    }

    // --- epilogue: quad scan -> per-lane top2 -> LDS -> compress ---
    __syncthreads();   // all waves done with pool before reuse
    int* Cls = (int*)pool;
    #pragma unroll
    for (int mf = 0; mf < 8; ++mf) {
        int k0 = 0, k1 = 0;
        #pragma unroll
        for (int nf = 0; nf < 4; ++nf) {
            float qm = fmaxf(fmaxf(acc[mf][nf][0], acc[mf][nf][1]),
                             fmaxf(acc[mf][nf][2], acc[mf][nf][3]));
            int key = (int)((__float_as_uint(qm) & 0xFFFF0000u)
                            | (unsigned)(wn*16 + nf*4 + lk));
            if (key > k0)      { k1 = k0; k0 = key; }
            else if (key > k1) { k1 = key; }
        }
        int row = wm*128 + mf*16 + l16;
        int ent = wn*4 + lk;
        Cls[row*33 + ent*2 + 0] = k0;
        Cls[row*33 + ent*2 + 1] = k1;
    }
    __syncthreads();

    {
        int row  = t >> 1, half = t & 1;
        int ks[4] = {0, 0, 0, 0};
        #pragma unroll
        for (int j = 0; j < 16; ++j)
            ins4(ks, Cls[row*33 + half*16 + j]);
        int grow = rc*256 + row;
        size_t base = (size_t)grow*NCAND + cc*8 + half*4;
        *reinterpret_cast<uint4*>(&cand[base]) =
            make_uint4((unsigned)ks[0], (unsigned)ks[1],
                       (unsigned)ks[2], (unsigned)ks[3]);
    }
}

// ---------------------------------------------------------------------------
// Kernel 3a: wave-parallel exact top-24 per row. [unchanged from round 12]
// ---------------------------------------------------------------------------
__global__ __launch_bounds__(256, 8)
void merge_topq(const unsigned* __restrict__ cand, int* __restrict__ quads)
{
    __shared__ u64 Wv[4*NKF];

    const int row  = blockIdx.x;
    const int t    = threadIdx.x;
    const int wid  = t >> 6, lane = t & 63;

    u64 a[13];
    #pragma unroll
    for (int i = 0; i < 13; ++i) a[i] = 0ull;

    const unsigned* rc = cand + (size_t)row*NCAND;
    #pragma unroll
    for (int i = 0; i < 13; ++i) {
        int off = i*64 + lane;
        if (off < 784) {
            int c = wid*784 + off;
            unsigned e = rc[c];
            u64 comb = ((u64)(e ^ 0x80000000u) << 32)
                     | (unsigned)(((c >> 3) << 6) | (e & 63u));
            pins64<13>(a, comb);
        }
    }

    u64 mywin = 0ull;
    for (int k = 0; k < NKF; ++k) {
        u64 h = a[0], r = h;
        #pragma unroll
        for (int m = 1; m < 64; m <<= 1) {
            u64 o = __shfl_xor(r, m);
            r = (o > r) ? o : r;
        }
        bool win = (h == r);
        #pragma unroll
        for (int j = 0; j < 12; ++j) a[j] = win ? a[j+1] : a[j];
        a[12] = win ? 0ull : a[12];
        mywin = (lane == k) ? r : mywin;
    }
    if (lane < NKF) Wv[wid*NKF + lane] = mywin;
    __syncthreads();

    if (wid == 0) {
        u64 b0 = Wv[lane];
        u64 b1 = (lane < 32) ? Wv[lane + 64] : 0ull;
        if (b1 > b0) { u64 tmp = b0; b0 = b1; b1 = tmp; }

        u64 fin = 0ull;
        for (int k = 0; k < NKF; ++k) {
            u64 h = b0, r = h;
            #pragma unroll
            for (int m = 1; m < 64; m <<= 1) {
                u64 o = __shfl_xor(r, m);
                r = (o > r) ? o : r;
            }
            bool win = (h == r);
            b0 = win ? b1 : b0;
            b1 = win ? 0ull : b1;
            fin = (lane == k) ? r : fin;
        }
        if (lane < NKF) quads[row*NKF + lane] = (int)(fin & 0xffffffffull);
    }
}

// ---------------------------------------------------------------------------
// Kernel 3b: dense exact rescore. One 16-lane group per dot. [unchanged]
// ---------------------------------------------------------------------------
__global__ __launch_bounds__(256, 8)
void rescore_exact(const int* __restrict__ quads, const int* __restrict__ wordid,
                   const float* __restrict__ weight, double* __restrict__ scores)
{
    const int g = (blockIdx.x * 256 + threadIdx.x) >> 4;
    const int l = threadIdx.x & 15;
    const int row = g / NDOT;
    const int ci  = g - row * NDOT;

    const int q   = quads[row*NKF + (ci >> 2)];
    const int col = q*4 + (ci & 3);
    const bool valid = (col < VOCAB);
    const int col_eff = valid ? col : 0;

    const float* qr = weight + (size_t)wordid[row]*KDIM;
    const float* wr = weight + (size_t)col_eff*KDIM;

    double a0 = 0.0, a1 = 0.0;
    #pragma unroll
    for (int k = 0; k < 4; ++k) {
        int sl = (l + 16*k) * 4;
        float4 qa = *reinterpret_cast<const float4*>(qr + sl);
        float4 wb = *reinterpret_cast<const float4*>(wr + sl);
        a0 += (double)qa.x * wb.x + (double)qa.z * wb.z;
        a1 += (double)qa.y * wb.y + (double)qa.w * wb.w;
    }
    if (l < 11) {
        int sl = (l + 64) * 4;
        float4 qa = *reinterpret_cast<const float4*>(qr + sl);
        float4 wb = *reinterpret_cast<const float4*>(wr + sl);
        a0 += (double)qa.x * wb.x + (double)qa.z * wb.z;
        a1 += (double)qa.y * wb.y + (double)qa.w * wb.w;
    }
    double a = a0 + a1;
    #pragma unroll
    for (int m = 1; m < 16; m <<= 1) a += __shfl_xor(a, m);

    if (l == 0) scores[g] = valid ? a : -1e300;
}

// ---------------------------------------------------------------------------
// Kernel 3c: per row, wave-parallel top-11 of the 96 exact scores. [unchanged]
// ---------------------------------------------------------------------------
__global__ __launch_bounds__(64, 8)
void final_select(const double* __restrict__ scores, const int* __restrict__ quads,
                  float* __restrict__ out)
{
    const int row  = blockIdx.x;
    const int lane = threadIdx.x;

    double v0 = -INFINITY, v1 = -INFINITY;
    int    c0 = 0x7fffffff, c1 = 0x7fffffff;
    if (lane < NDOT/2) {
        int i0 = lane*2, i1 = lane*2 + 1;
        v0 = scores[(size_t)row*NDOT + i0];
        v1 = scores[(size_t)row*NDOT + i1];
        c0 = quads[row*NKF + (i0 >> 2)]*4 + (i0 & 3);
        c1 = quads[row*NKF + (i1 >> 2)]*4 + (i1 & 3);
    }

    for (int kk = 0; kk < TOPK + 1; ++kk) {
        bool sel = (v0 > v1) || (v0 == v1 && c0 < c1);
        double bv = sel ? v0 : v1;
        int    bc = sel ? c0 : c1;
        #pragma unroll
        for (int m = 1; m < 64; m <<= 1) {
            double ov = __shfl_xor(bv, m);
            int    oc = __shfl_xor(bc, m);
            if (ov > bv || (ov == bv && oc < bc)) { bv = ov; bc = oc; }
        }
        if (kk >= 1 && lane == 0) {
            out[(size_t)row*TOPK + (kk-1)] = (float)bv;
            out[(size_t)BATCH*TOPK + (size_t)row*TOPK + (kk-1)] = (float)bc;
        }
        if (c0 == bc) v0 = -INFINITY;
        if (c1 == bc) v1 = -INFINITY;
    }
}

extern "C" void kernel_launch(void* const* d_in, const int* in_sizes, int n_in,
                              void* d_out, int out_size, void* d_ws, size_t ws_size,
                              hipStream_t stream) {
    const int*   wordid = (const int*)d_in[0];
    const float* weight = (const float*)d_in[1];
    float* out = (float*)d_out;

    const size_t SZ_A = (size_t)NCB_A * NKB * 64 * 16;   // 655,360 B

    char* p = (char*)d_ws;
    ushort*   ws_a = (ushort*)p;  p += SZ_A;
    unsigned* cand = (unsigned*)p;               // 12.8 MB

    int*    quads  = (int*)ws_a;      // ws_a dead after sim_gemm (96 KB)
    double* scores = (double*)cand;   // cand dead after merge_topq (768 KB)

    convert_a<<<NCB_A/4, 256, 0, stream>>>(wordid, weight, ws_a);
    sim_gemm<<<NCC*4, 512, 0, stream>>>(ws_a, weight, cand);
    merge_topq<<<BATCH, 256, 0, stream>>>(cand, quads);
    rescore_exact<<<(BATCH*NDOT)/16, 256, 0, stream>>>(quads, wordid, weight, scores);
    final_select<<<BATCH, 64, 0, stream>>>(scores, quads, out);
}

// Round 18
// 155.026 us; speedup vs baseline: 2.2125x; 2.2125x over previous
//
#include <hip/hip_runtime.h>
#include <math.h>

#define BATCH 1024
#define VOCAB 100000
#define KDIM  300
#define TOPK  10

#define NKB    10            // K blocks of 32 (K padded 300 -> 320)
#define NCB_B  6272          // vocab col-blocks of 16, pad vocab to 100352
#define NCB_A  64            // 1024 rows / 16
#define NCC    392           // 256-col chunks (NCB_B/16)
#define NCAND  (NCC*8)       // 3136 candidate u32s per row (8 per chunk)
#define NKF    24            // final quad rescore set -> 96 cols
#define NDOT   (NKF*4)       // 96 exact dots per row

typedef __attribute__((ext_vector_type(8))) short bf16x8;
typedef __attribute__((ext_vector_type(4))) float f32x4;
typedef unsigned long long u64;

#define GL2LDS(gsrc, ldst)                                                    \
    __builtin_amdgcn_global_load_lds(                                         \
        (const __attribute__((address_space(1))) void*)(gsrc),                \
        (__attribute__((address_space(3))) void*)(ldst), 16, 0, 0)

__device__ __forceinline__ ushort f2bf(float f) {
    union { float f; unsigned u; } v; v.f = f;
    unsigned r = v.u + 0x7FFFu + ((v.u >> 16) & 1u);  // RNE
    return (ushort)(r >> 16);
}

// depth-4 descending insert, SIGNED keys (sentinel 0)
__device__ __forceinline__ void ins4(int (&l)[4], int e) {
    if (e <= l[3]) return;
    bool g0 = e > l[0], g1 = e > l[1], g2 = e > l[2];
    l[3] = g2 ? l[2] : e;
    l[2] = g2 ? (g1 ? l[1] : e) : l[2];
    l[1] = g1 ? (g0 ? l[0] : e) : l[1];
    l[0] = g0 ? e : l[0];
}

// descending u64 insert, depth N, fully unrolled (sentinel 0)
template<int N>
__device__ __forceinline__ void pins64(u64 (&ks)[N], u64 k) {
    if (k <= ks[N-1]) return;
    #pragma unroll
    for (int p = N-1; p >= 0; --p) {
        bool gt  = k > ks[p];
        bool gtp = (p > 0) ? (k > ks[p-1]) : false;
        ks[p] = gt ? (gtp ? ks[p-1] : k) : ks[p];
    }
}

// ---------------------------------------------------------------------------
// Kernel 1: LDS-free fragment packer (A + B). [r13 version, restored]
//   B frag (kb, cb):   ws_b[((kb*NCB_B + cb)*64 + lane)*8 .. +7]
//   A frag (kb, rb16): ws_a[((kb*64   + rb16)*64 + lane)*8 .. +7]
// ---------------------------------------------------------------------------
__global__ __launch_bounds__(256)
void convert_frags(const int* __restrict__ wordid, const float* __restrict__ weight,
                   ushort* __restrict__ ws_b, ushort* __restrict__ ws_a, int nb4)
{
    const int t   = threadIdx.x;
    const int w   = t >> 6, l = t & 63;
    const int bid = blockIdx.x;
    const bool is_a = (bid >= nb4);
    const int cb  = (is_a ? (bid - nb4) : bid) * 4 + w;
    ushort* dst = is_a ? ws_a : ws_b;
    const int kstride = is_a ? 64 : NCB_B;

    const int r16  = l & 15;
    const int ksub = (l >> 4) * 8;

    const int row = is_a ? wordid[cb*16 + r16] : (cb*16 + r16);
    const bool vr = (row < VOCAB);
    const float* src = weight + (size_t)(vr ? row : 0) * KDIM;

    #pragma unroll
    for (int kb = 0; kb < NKB; ++kb) {
        const int k0 = kb*32 + ksub;
        float4 a = make_float4(0.f,0.f,0.f,0.f);
        float4 b = make_float4(0.f,0.f,0.f,0.f);
        if (vr) {
            if (k0 + 8 <= KDIM) {
                a = *reinterpret_cast<const float4*>(src + k0);
                b = *reinterpret_cast<const float4*>(src + k0 + 4);
            } else if (k0 + 4 <= KDIM) {
                a = *reinterpret_cast<const float4*>(src + k0);
            }
        }
        uint4 o;
        o.x = (unsigned)f2bf(a.x) | ((unsigned)f2bf(a.y) << 16);
        o.y = (unsigned)f2bf(a.z) | ((unsigned)f2bf(a.w) << 16);
        o.z = (unsigned)f2bf(b.x) | ((unsigned)f2bf(b.y) << 16);
        o.w = (unsigned)f2bf(b.z) | ((unsigned)f2bf(b.w) << 16);
        *reinterpret_cast<uint4*>(&dst[((size_t)kb*kstride + cb)*512 + (size_t)l*8]) = o;
    }
}

// ---------------------------------------------------------------------------
// Kernel 2: 256x256 tile, de-barriered K-loop. [r13 version, restored —
// best of 9 measured schedule/placement variants at 93 us]
// ---------------------------------------------------------------------------
__global__ __launch_bounds__(512, 2)
void sim_gemm(const ushort* __restrict__ ws_a, const ushort* __restrict__ ws_b,
              unsigned* __restrict__ cand)
{
    __shared__ __align__(16) char pool[131072];

    const int id = blockIdx.x;
    const int cc = (id & 7) + ((id >> 5) << 3);   // col-chunk 0..391
    const int rc = (id >> 3) & 3;                 // row-chunk 0..3

    const int t    = threadIdx.x;
    const int wid  = t >> 6, lane = t & 63;
    const int wm   = wid >> 2, wn = wid & 3;
    const int l16  = lane & 15, lk = lane >> 4;

    auto stage_slot = [&](int kt, int slot, int buf) {
        char* ldst = pool + buf*65536 + slot*1024;
        const ushort* src;
        if (slot < 32) {
            src = ws_a + (((size_t)(kt*2 + (slot>>4))*64) + rc*16 + (slot & 15))*512
                       + (size_t)lane*8;
        } else {
            int s2 = slot - 32;
            src = ws_b + (((size_t)(kt*2 + (s2>>4))*NCB_B) + cc*16 + (s2 & 15))*512
                       + (size_t)lane*8;
        }
        GL2LDS(src, (ushort*)ldst);
    };

    f32x4 acc[8][4] = {};

    // prologue: stage K-tile 0 into buffer 0, drain, barrier
    #pragma unroll
    for (int j = 0; j < 8; ++j) stage_slot(0, wid*8 + j, 0);
    asm volatile("s_waitcnt vmcnt(0)" ::: "memory");
    __builtin_amdgcn_s_barrier();
    asm volatile("" ::: "memory");

    for (int kt = 0; kt < 5; ++kt) {
        const int buf = kt & 1;
        const ushort* Ab = (const ushort*)(pool + buf*65536);
        const ushort* Bb = (const ushort*)(pool + buf*65536 + 32768);

        if (kt < 4) {
            #pragma unroll
            for (int j = 0; j < 8; ++j)
                stage_slot(kt + 1, wid*8 + j, buf ^ 1);
        }

        bf16x8 bfr[2][4];
        #pragma unroll
        for (int kb = 0; kb < 2; ++kb)
            #pragma unroll
            for (int nf = 0; nf < 4; ++nf)
                bfr[kb][nf] = *reinterpret_cast<const bf16x8*>(
                    Bb + (size_t)(kb*16 + wn*4 + nf)*512 + lane*8);

        #pragma unroll
        for (int p = 0; p < 4; ++p) {
            bf16x8 af[2][2];
            #pragma unroll
            for (int kb = 0; kb < 2; ++kb)
                #pragma unroll
                for (int m2 = 0; m2 < 2; ++m2)
                    af[kb][m2] = *reinterpret_cast<const bf16x8*>(
                        Ab + (size_t)(kb*16 + wm*8 + p*2 + m2)*512 + lane*8);

            __builtin_amdgcn_s_setprio(1);
            #pragma unroll
            for (int m2 = 0; m2 < 2; ++m2)
                #pragma unroll
                for (int nf = 0; nf < 4; ++nf) {
                    acc[p*2+m2][nf] = __builtin_amdgcn_mfma_f32_16x16x32_bf16(
                        bfr[0][nf], af[0][m2], acc[p*2+m2][nf], 0, 0, 0);
                    acc[p*2+m2][nf] = __builtin_amdgcn_mfma_f32_16x16x32_bf16(
                        bfr[1][nf], af[1][m2], acc[p*2+m2][nf], 0, 0, 0);
                }
            __builtin_amdgcn_s_setprio(0);
        }

        if (kt < 4) {
            asm volatile("s_waitcnt vmcnt(0)" ::: "memory");
            __builtin_amdgcn_s_barrier();
            asm volatile("" ::: "memory");
        }
    }

    // --- epilogue: quad scan -> per-lane top2 -> LDS -> compress ---
    __syncthreads();
    int* Cls = (int*)pool;
    #pragma unroll
    for (int mf = 0; mf < 8; ++mf) {
        int k0 = 0, k1 = 0;
        #pragma unroll
        for (int nf = 0; nf < 4; ++nf) {
            float qm = fmaxf(fmaxf(acc[mf][nf][0], acc[mf][nf][1]),
                             fmaxf(acc[mf][nf][2], acc[mf][nf][3]));
            int key = (int)((__float_as_uint(qm) & 0xFFFF0000u)
                            | (unsigned)(wn*16 + nf*4 + lk));
            if (key > k0)      { k1 = k0; k0 = key; }
            else if (key > k1) { k1 = key; }
        }
        int row = wm*128 + mf*16 + l16;
        int ent = wn*4 + lk;
        Cls[row*33 + ent*2 + 0] = k0;
        Cls[row*33 + ent*2 + 1] = k1;
    }
    __syncthreads();

    {
        int row  = t >> 1, half = t & 1;
        int ks[4] = {0, 0, 0, 0};
        #pragma unroll
        for (int j = 0; j < 16; ++j)
            ins4(ks, Cls[row*33 + half*16 + j]);
        int grow = rc*256 + row;
        size_t base = (size_t)grow*NCAND + cc*8 + half*4;
        *reinterpret_cast<uint4*>(&cand[base]) =
            make_uint4((unsigned)ks[0], (unsigned)ks[1],
                       (unsigned)ks[2], (unsigned)ks[3]);
    }
}

// ---------------------------------------------------------------------------
// Kernel 3 (round 18): FUSED tail — merge (r12 wave-parallel extraction) +
// exact fp64 rescore (16 groups x 6 dots, q-row in LDS) + wave-parallel
// top-11 select. quads/scores never touch global; 2 dispatch gaps removed.
// ---------------------------------------------------------------------------
__global__ __launch_bounds__(256, 4)
void topk_finalize(const unsigned* __restrict__ cand, const int* __restrict__ wordid,
                   const float* __restrict__ weight, float* __restrict__ out)
{
    __shared__ u64    Wv[4*NKF];
    __shared__ int    Qq[NKF];
    __shared__ float  Qrow[304];
    __shared__ double Rs[NDOT];
    __shared__ int    Rc[NDOT];

    const int row  = blockIdx.x;
    const int t    = threadIdx.x;
    const int wid  = t >> 6, lane = t & 63;

    // preload q row (75 float4s = 300 floats)
    if (t < 75)
        *reinterpret_cast<float4*>(&Qrow[t*4]) =
            *reinterpret_cast<const float4*>(weight + (size_t)wordid[row]*KDIM + t*4);

    // --- phase 1: merge 3136 cands -> exact top-24 quads (r12 logic) ---
    u64 a[13];
    #pragma unroll
    for (int i = 0; i < 13; ++i) a[i] = 0ull;

    const unsigned* rc = cand + (size_t)row*NCAND;
    #pragma unroll
    for (int i = 0; i < 13; ++i) {
        int off = i*64 + lane;
        if (off < 784) {
            int c = wid*784 + off;
            unsigned e = rc[c];
            u64 comb = ((u64)(e ^ 0x80000000u) << 32)
                     | (unsigned)(((c >> 3) << 6) | (e & 63u));
            pins64<13>(a, comb);
        }
    }

    u64 mywin = 0ull;
    for (int k = 0; k < NKF; ++k) {
        u64 h = a[0], r = h;
        #pragma unroll
        for (int m = 1; m < 64; m <<= 1) {
            u64 o = __shfl_xor(r, m);
            r = (o > r) ? o : r;
        }
        bool win = (h == r);
        #pragma unroll
        for (int j = 0; j < 12; ++j) a[j] = win ? a[j+1] : a[j];
        a[12] = win ? 0ull : a[12];
        mywin = (lane == k) ? r : mywin;
    }
    if (lane < NKF) Wv[wid*NKF + lane] = mywin;
    __syncthreads();

    if (wid == 0) {
        u64 b0 = Wv[lane];
        u64 b1 = (lane < 32) ? Wv[lane + 64] : 0ull;
        if (b1 > b0) { u64 tmp = b0; b0 = b1; b1 = tmp; }

        u64 fin = 0ull;
        for (int k = 0; k < NKF; ++k) {
            u64 h = b0, r = h;
            #pragma unroll
            for (int m = 1; m < 64; m <<= 1) {
                u64 o = __shfl_xor(r, m);
                r = (o > r) ? o : r;
            }
            bool win = (h == r);
            b0 = win ? b1 : b0;
            b1 = win ? 0ull : b1;
            fin = (lane == k) ? r : fin;
        }
        if (lane < NKF) Qq[lane] = (int)(fin & 0xffffffffull);
    }
    __syncthreads();

    // --- phase 2: exact fp64 rescore, group g of 16 lanes per dot ---
    {
        const int g = t >> 4, l = t & 15;
        for (int ci = g; ci < NDOT; ci += 16) {
            const int q   = Qq[ci >> 2];
            const int col = q*4 + (ci & 3);
            const bool valid = (col < VOCAB);
            const float* wr = weight + (size_t)(valid ? col : 0)*KDIM;

            double a0 = 0.0, a1 = 0.0;
            #pragma unroll
            for (int k = 0; k < 4; ++k) {
                int sl = (l + 16*k) * 4;
                float4 qa = *reinterpret_cast<const float4*>(&Qrow[sl]);
                float4 wb = *reinterpret_cast<const float4*>(wr + sl);
                a0 += (double)qa.x * wb.x + (double)qa.z * wb.z;
                a1 += (double)qa.y * wb.y + (double)qa.w * wb.w;
            }
            if (l < 11) {
                int sl = (l + 64) * 4;
                float4 qa = *reinterpret_cast<const float4*>(&Qrow[sl]);
                float4 wb = *reinterpret_cast<const float4*>(wr + sl);
                a0 += (double)qa.x * wb.x + (double)qa.z * wb.z;
                a1 += (double)qa.y * wb.y + (double)qa.w * wb.w;
            }
            double s = a0 + a1;
            #pragma unroll
            for (int m = 1; m < 16; m <<= 1) s += __shfl_xor(s, m);
            if (l == 0) { Rs[ci] = valid ? s : -1e300; Rc[ci] = valid ? col : 0x7fffffff; }
        }
    }
    __syncthreads();

    // --- phase 3: wave 0 selects top-11 (numpy tie-break), drop rank-1 ---
    if (wid == 0) {
        double v0 = -INFINITY, v1 = -INFINITY;
        int    c0 = 0x7fffffff, c1 = 0x7fffffff;
        if (lane < NDOT/2) {
            v0 = Rs[lane*2];     c0 = Rc[lane*2];
            v1 = Rs[lane*2 + 1]; c1 = Rc[lane*2 + 1];
        }
        for (int kk = 0; kk < TOPK + 1; ++kk) {
            bool sel = (v0 > v1) || (v0 == v1 && c0 < c1);
            double bv = sel ? v0 : v1;
            int    bc = sel ? c0 : c1;
            #pragma unroll
            for (int m = 1; m < 64; m <<= 1) {
                double ov = __shfl_xor(bv, m);
                int    oc = __shfl_xor(bc, m);
                if (ov > bv || (ov == bv && oc < bc)) { bv = ov; bc = oc; }
            }
            if (kk >= 1 && lane == 0) {
                out[(size_t)row*TOPK + (kk-1)] = (float)bv;
                out[(size_t)BATCH*TOPK + (size_t)row*TOPK + (kk-1)] = (float)bc;
            }
            if (c0 == bc) v0 = -INFINITY;
            if (c1 == bc) v1 = -INFINITY;
        }
    }
}

extern "C" void kernel_launch(void* const* d_in, const int* in_sizes, int n_in,
                              void* d_out, int out_size, void* d_ws, size_t ws_size,
                              hipStream_t stream) {
    const int*   wordid = (const int*)d_in[0];
    const float* weight = (const float*)d_in[1];
    float* out = (float*)d_out;

    const size_t SZ_B = (size_t)NCB_B * NKB * 64 * 16;   // 64,225,280 B
    const size_t SZ_A = (size_t)NCB_A * NKB * 64 * 16;   //    655,360 B

    char* p = (char*)d_ws;
    ushort*   ws_b = (ushort*)p;  p += SZ_B;
    ushort*   ws_a = (ushort*)p;  p += SZ_A;
    unsigned* cand = (unsigned*)p;               // 12.8 MB

    convert_frags<<<NCB_B/4 + NCB_A/4, 256, 0, stream>>>(wordid, weight, ws_b, ws_a, NCB_B/4);
    sim_gemm<<<NCC*4, 512, 0, stream>>>(ws_a, ws_b, cand);
    topk_finalize<<<BATCH, 256, 0, stream>>>(cand, wordid, weight, out);
}